// Round 11
// baseline (186.850 us; speedup 1.0000x reference)
//
#include <hip/hip_runtime.h>
#include <math.h>

// R11: in-wave rFFT unpack — kill the writeback/barrier/re-read loop.
// R10 (95us, best): VALU issue ~41us, HBM ~11us, ~54us latency stall at 16
// waves/CU (LDS-capped: Z 33K + xs 7.6K = exactly 4 blocks/CU). The only
// reason phase-2 results went back to LDS was pairing p with 256-p across
// threads. Fix: lane remap th=tid&15, fi=tid>>4 -> a frame's 16 workers are
// consecutive lanes of ONE wave; partner (column 16-th, register 15-r) is
// in-wave -> one __shfl per r. th=0 self-pairs via static P0R table.
// Drops: barrier #3, 16 LDS writebacks, 16 epilogue reads (~110->~53 LDS
// ops/thread, 3->2 barriers). Unpack twiddle T = Tth*CK[k2] (one cospif
// pair/thread + compile-time CK table). Stores: 16B/row/inst (4 fi/wave),
// same-block L2 merge expected - watch WRITE_SIZE.
// Kept (validated): R10 staging, on-the-fly window/tw256 cospif, SLOT
// transpose, fast_atan2, LDS-xs patch (bit-exact v5 order), XCD swizzle,
// launch_bounds(256,4), LDS 40624B = 4 blocks/CU.

#define BATCH 16
#define NSAMP 160000
#define NF 257
#define NT 1603
#define KLEN 400
#define INC 100
#define PADL 300
#define EPSF 1.1920928955078125e-7f
#define TAU 1e-2f

#define FPB 16                            // frames per block
#define ZSTR 258                          // complex stride per frame row
#define XSPAN ((FPB - 1) * INC + KLEN)    // 1900
#define NTB ((NT + FPB - 1) / FPB)        // 101
#define SLOT(j, k) (16 * (j) + (((k) + (j)) & 15))

__device__ __forceinline__ float2 cmul(float2 a, float2 b) {
  return make_float2(a.x * b.x - a.y * b.y, a.x * b.y + a.y * b.x);
}

// 16-point DIF FFT in registers; output a[r] = F[brev4(r)].
__device__ __forceinline__ void fft16_dif(float2* a) {
  const float C1 = 0.92387953251128674f;   // cos(pi/8)
  const float S1 = 0.38268343236508978f;   // sin(pi/8)
  const float R2 = 0.70710678118654752f;   // sqrt(2)/2
  {                                        // span 8, tw = w16^j
    const float2 W[8] = {{1.f, 0.f},  {C1, -S1},  {R2, -R2},  {S1, -C1},
                         {0.f, -1.f}, {-S1, -C1}, {-R2, -R2}, {-C1, -S1}};
    #pragma unroll
    for (int j = 0; j < 8; ++j) {
      float2 u = a[j], v = a[j + 8];
      a[j] = make_float2(u.x + v.x, u.y + v.y);
      float2 d = make_float2(u.x - v.x, u.y - v.y);
      a[j + 8] = cmul(d, W[j]);
    }
  }
  {                                        // span 4, tw = w8^j
    const float2 W[4] = {{1.f, 0.f}, {R2, -R2}, {0.f, -1.f}, {-R2, -R2}};
    #pragma unroll
    for (int h = 0; h < 16; h += 8)
      #pragma unroll
      for (int j = 0; j < 4; ++j) {
        float2 u = a[h + j], v = a[h + j + 4];
        a[h + j] = make_float2(u.x + v.x, u.y + v.y);
        float2 d = make_float2(u.x - v.x, u.y - v.y);
        a[h + j + 4] = cmul(d, W[j]);
      }
  }
  #pragma unroll
  for (int q = 0; q < 16; q += 4) {        // span 2, tw = {1, -i}
    float2 u0 = a[q], v0 = a[q + 2];
    a[q] = make_float2(u0.x + v0.x, u0.y + v0.y);
    a[q + 2] = make_float2(u0.x - v0.x, u0.y - v0.y);
    float2 u1 = a[q + 1], v1 = a[q + 3];
    a[q + 1] = make_float2(u1.x + v1.x, u1.y + v1.y);
    float2 d = make_float2(u1.x - v1.x, u1.y - v1.y);
    a[q + 3] = make_float2(d.y, -d.x);     // *(-i)
  }
  #pragma unroll
  for (int q = 0; q < 16; q += 2) {        // span 1
    float2 u = a[q], v = a[q + 1];
    a[q] = make_float2(u.x + v.x, u.y + v.y);
    a[q + 1] = make_float2(u.x - v.x, u.y - v.y);
  }
}

// atan2 via deg-11 odd minimax on [0,1] (max err ~2.4e-6 rad; thr = 1.05).
__device__ __forceinline__ float fast_atan2(float y, float x) {
  float ax = fabsf(x), ay = fabsf(y);
  float mx = fmaxf(ax, ay), mn = fminf(ax, ay);
  float t = mn * __builtin_amdgcn_rcpf(fmaxf(mx, 1e-37f));
  float s = t * t;
  float p = fmaf(s, -0.01172120f, 0.05265332f);
  p = fmaf(s, p, -0.11643287f);
  p = fmaf(s, p, 0.19354346f);
  p = fmaf(s, p, -0.33262347f);
  p = fmaf(s, p, 0.99997726f);
  float r = t * p;
  if (ay > ax) r = 1.57079632679489662f - r;
  if (x < 0.f) r = 3.14159265358979324f - r;
  return (y < 0.f) ? -r : r;
}

// mag/phase emit; branch-cut patch: bit-exact v5 sequential-fmaf from LDS xs.
__device__ __forceinline__ void emit_fp(float rr, float ii, int ff,
                                        const float* __restrict__ w,
                                        const float* xf,
                                        float* __restrict__ out,
                                        long o, long plane) {
  float ie = ii + EPSF, re = rr + EPSF;
  if (fabsf(ie) < TAU && re < TAU) {       // cold path, ~2 pts/block
    const float* wr = w + (long)ff * KLEN;
    const float* wi = w + (long)(257 + ff) * KLEN;
    float r2 = 0.f, i2 = 0.f;
    for (int k = 0; k < KLEN; ++k) {       // sequential k (v5 rounding class)
      float xv = xf[k];
      r2 = fmaf(wr[k], xv, r2);
      i2 = fmaf(wi[k], xv, i2);
    }
    rr = r2; ii = i2;
  }
  out[o] = sqrtf(fmaxf(rr * rr + ii * ii, EPSF));
  out[o + plane] = fast_atan2(ii + EPSF, rr + EPSF);
}

__global__ __launch_bounds__(256, 4)
void stft_fft11(const float* __restrict__ x, const float* __restrict__ w,
                float* __restrict__ out) {
  __shared__ float2 Z[FPB * ZSTR];          // 33024 B
  __shared__ __align__(16) float xs[XSPAN]; // 7600 B   (total 40624 <= 40960)

  const int tid = threadIdx.x;
  const int b = blockIdx.y;
  const int th = tid & 15;                  // worker/column (consecutive lanes)
  const int fi = tid >> 4;                  // frame 0..15 (4 frames per wave)

  // m204 bijective XCD swizzle over 101 t-chunks (q=12, r=5)
  const int u = blockIdx.x;
  const int xcd = u & 7;
  const int tb = ((xcd < 5) ? xcd * 13 : 65 + (xcd - 5) * 12) + (u >> 3);
  const int t0 = tb * FPB;

  // ---- stage xs (vectorized, zero-padded) ----
  const long xb = (long)b * NSAMP;
  const int base = t0 * INC - PADL;
  for (int r = 0; r < 2; ++r) {
    int i4 = r * 256 + tid;
    if (4 * i4 < XSPAN) {
      int g = base + 4 * i4;
      float4 v;
      if (g >= 0 && g + 3 < NSAMP) {
        v = *(const float4*)(x + xb + g);
      } else {
        v.x = (g + 0 >= 0 && g + 0 < NSAMP) ? x[xb + g + 0] : 0.f;
        v.y = (g + 1 >= 0 && g + 1 < NSAMP) ? x[xb + g + 1] : 0.f;
        v.z = (g + 2 >= 0 && g + 2 < NSAMP) ? x[xb + g + 2] : 0.f;
        v.w = (g + 3 >= 0 && g + 3 < NSAMP) ? x[xb + g + 3] : 0.f;
      }
      *(float4*)&xs[4 * i4] = v;
    }
  }
  __syncthreads();

  // ---- phase 1: windowed LDS load (window on the fly) -> register FFT ----
  float2 a[16];
  const float* xf = &xs[fi * INC];
  #pragma unroll
  for (int n1 = 0; n1 < 12; ++n1) {         // n = 32*n1+2*th <= 382 < 400
    int n = 32 * n1 + 2 * th;
    float2 xv = *(const float2*)&xf[n];
    float w0 = fmaf(-0.46f, cospif((float)n * 0.005f), 0.54f);
    float w1 = fmaf(-0.46f, cospif((float)(n + 1) * 0.005f), 0.54f);
    a[n1] = make_float2(xv.x * w0, xv.y * w1);
  }
  {
    int n = 384 + 2 * th;                   // n1 = 12: valid iff th <= 7
    if (n < KLEN) {
      float2 xv = *(const float2*)&xf[n];
      float w0 = fmaf(-0.46f, cospif((float)n * 0.005f), 0.54f);
      float w1 = fmaf(-0.46f, cospif((float)(n + 1) * 0.005f), 0.54f);
      a[12] = make_float2(xv.x * w0, xv.y * w1);
    } else {
      a[12] = make_float2(0.f, 0.f);
    }
  }
  a[13] = a[14] = a[15] = make_float2(0.f, 0.f);   // y[n]=0, n>=416

  fft16_dif(a);                             // a[r] = F1[th][brev4(r)]

  static const int BR[16] = {0, 8, 4, 12, 2, 10, 6, 14,
                             1, 9, 5, 13, 3, 11, 7, 15};
  float2* Zf = Z + fi * ZSTR;
  #pragma unroll
  for (int r = 0; r < 16; ++r) {            // x w256^{th*k1} on the fly
    const int k1 = BR[r];
    float2 v;
    if (k1 == 0) {
      v = a[r];
    } else {
      float aa = (float)(th * k1) * (1.0f / 128.0f);
      v = cmul(a[r], make_float2(cospif(aa), -sinpif(aa)));
    }
    Zf[SLOT(th, k1)] = v;
  }
  __syncthreads();                          // (transpose is wave-local; kept
                                            //  as barrier for safety)

  // ---- phase 2: SLOT column read -> register FFT over n2 ----
  float2 g[16];
  #pragma unroll
  for (int n2 = 0; n2 < 16; ++n2) g[n2] = Zf[SLOT(n2, th)];
  fft16_dif(g);                             // g[r] = Zspec[16*BR[r] + th]

  // ---- in-register rFFT unpack + mag/phase + direct store ----
  // partner of p=16*BR[r]+th: lane'=(16-th)&15 (same fi), reg 15-r (th>=1);
  // th==0: self-lane reg P0R[r] (p'=16*((16-k2)&15)).
  static const int P0R[16] = {0, 1, 3, 2, 7, 6, 5, 4,
                              15, 14, 13, 12, 11, 10, 9, 8};
  static const float2 CK[16] = {              // e^{-i*pi*k2/16}
    {1.f, 0.f},
    {0.98078528040323044913f, -0.19509032201612826785f},
    {0.92387953251128675613f, -0.38268343236508977173f},
    {0.83146961230254523708f, -0.55557023301960222474f},
    {0.70710678118654752440f, -0.70710678118654752440f},
    {0.55557023301960222474f, -0.83146961230254523708f},
    {0.38268343236508977173f, -0.92387953251128675613f},
    {0.19509032201612826785f, -0.98078528040323044913f},
    {0.f, -1.f},
    {-0.19509032201612826785f, -0.98078528040323044913f},
    {-0.38268343236508977173f, -0.92387953251128675613f},
    {-0.55557023301960222474f, -0.83146961230254523708f},
    {-0.70710678118654752440f, -0.70710678118654752440f},
    {-0.83146961230254523708f, -0.55557023301960222474f},
    {-0.92387953251128675613f, -0.38268343236508977173f},
    {-0.98078528040323044913f, -0.19509032201612826785f}};

  const int lane = tid & 63;
  const int pl = ((16 - th) & 15) | (lane & 48);  // partner lane (same fi)
  float tha = (float)th * (1.0f / 256.0f);
  float2 Tth = make_float2(cospif(tha), -sinpif(tha));   // e^{-i*pi*th/256}

  const long plane = (long)BATCH * NF * NT;
  const long pb = (long)b * NF * NT;
  const int tt = t0 + fi;                   // uniform per fi group

  #pragma unroll
  for (int r = 0; r < 16; ++r) {
    const int k2 = BR[r];
    float2 z0 = g[r];
    float2 zsh = make_float2(__shfl(g[15 - r].x, pl),
                             __shfl(g[15 - r].y, pl));
    float2 z1 = (th == 0) ? g[P0R[r]] : zsh;
    if (tt < NT) {
      const int p = 16 * k2 + th;
      float2 T = cmul(Tth, CK[k2]);         // e^{-i*pi*p/256}
      float2 ze = make_float2(0.5f * (z0.x + z1.x), 0.5f * (z0.y - z1.y));
      float2 zo = make_float2(0.5f * (z0.y + z1.y), 0.5f * (z1.x - z0.x));
      float2 tz = cmul(zo, T);
      emit_fp(ze.x + tz.x, ze.y + tz.y, p, w, xf, out,
              pb + (long)p * NT + tt, plane);
      if (th == 0 && r == 0) {              // Y[256] = Re Z0 - Im Z0
        emit_fp(z0.x - z0.y, 0.f, 256, w, xf, out,
                pb + (long)256 * NT + tt, plane);
      }
    }
  }
}

extern "C" void kernel_launch(void* const* d_in, const int* in_sizes, int n_in,
                              void* d_out, int out_size, void* d_ws, size_t ws_size,
                              hipStream_t stream) {
  const float* x = (const float*)d_in[0];   // (16, 160000) fp32
  const float* w = (const float*)d_in[1];   // (514, 1, 400) fp32
  float* out = (float*)d_out;

  dim3 grid(NTB, BATCH);                    // 101 x 16 = 1616 blocks
  stft_fft11<<<grid, dim3(256), 0, stream>>>(x, w, out);
}